// Round 1
// baseline (6406.433 us; speedup 1.0000x reference)
//
#include <hip/hip_runtime.h>
#include <cstdint>
#include <cstddef>

#define LN_EPS 1e-5f

// ---------------------------------------------------------------------------
// Shared helpers
// ---------------------------------------------------------------------------

// Accumulate h[0..127] += x[0..31] * W1[segBase+k][j], x loaded from src (32
// contiguous floats). W1 staged in LDS (row-major [128][128]).
__device__ __forceinline__ void accum_segment(float (&h)[128],
                                              const float* __restrict__ src,
                                              const float* __restrict__ sW1,
                                              int segBase)
{
    const float4* s4 = reinterpret_cast<const float4*>(src);
#pragma unroll 1
    for (int q = 0; q < 8; q++) {
        float4 xv = s4[q];
        const float* w = &sW1[(segBase + q * 4) * 128];
#pragma unroll
        for (int j = 0; j < 128; j++) {
            float a = h[j];
            a = fmaf(xv.x, w[j], a);
            a = fmaf(xv.y, w[128 + j], a);
            a = fmaf(xv.z, w[256 + j], a);
            a = fmaf(xv.w, w[384 + j], a);
            h[j] = a;
        }
    }
}

// o[n] = b2[n] + sum_j h[j] * W2[j][n]   (W2 row-major [128][32], global mem,
// uniform address -> scalar loads through constant cache)
__device__ __forceinline__ void layer2(const float (&h)[128],
                                       const float* __restrict__ W2,
                                       const float* __restrict__ b2,
                                       float (&o)[32])
{
#pragma unroll
    for (int n = 0; n < 32; n++) o[n] = b2[n];
#pragma unroll
    for (int j = 0; j < 128; j++) {
        float hv = h[j];
#pragma unroll
        for (int n = 0; n < 32; n++) o[n] = fmaf(hv, W2[j * 32 + n], o[n]);
    }
}

// y = LN(relu(o)) * gamma + beta; store 32 floats to dst.
__device__ __forceinline__ void relu_ln_store(float (&o)[32],
                                              const float* __restrict__ gamma,
                                              const float* __restrict__ beta,
                                              float* __restrict__ dst,
                                              float (&y)[32])
{
    float mu = 0.f;
#pragma unroll
    for (int n = 0; n < 32; n++) { o[n] = fmaxf(o[n], 0.f); mu += o[n]; }
    mu *= (1.f / 32.f);
    float var = 0.f;
#pragma unroll
    for (int n = 0; n < 32; n++) { float d = o[n] - mu; var += d * d; }
    var *= (1.f / 32.f);
    float rs = rsqrtf(var + LN_EPS);
#pragma unroll
    for (int n = 0; n < 32; n++) y[n] = (o[n] - mu) * rs * gamma[n] + beta[n];
    float4* d4 = reinterpret_cast<float4*>(dst);
#pragma unroll
    for (int q = 0; q < 8; q++)
        d4[q] = make_float4(y[4 * q], y[4 * q + 1], y[4 * q + 2], y[4 * q + 3]);
}

// ---------------------------------------------------------------------------
// Edge model: e_in = [node[col], node[row], edge_attr, global[batch[row]]]
// edge_new = LN(relu(relu(e_in@W1+b1)@W2+b2)); atomic send/recv aggregation.
// ---------------------------------------------------------------------------
__global__ __launch_bounds__(256, 2)
void edge_kernel(const float* __restrict__ edge_attr,
                 const float* __restrict__ node_attr,
                 const float* __restrict__ global_attr,
                 const int* __restrict__ edge_index,
                 const int* __restrict__ batch,
                 const float* __restrict__ W1, const float* __restrict__ b1,
                 const float* __restrict__ W2, const float* __restrict__ b2,
                 const float* __restrict__ gamma, const float* __restrict__ beta,
                 float* __restrict__ edge_out,
                 float* __restrict__ send_agg, float* __restrict__ recv_agg,
                 int E)
{
    __shared__ float sW1[16384];   // 64 KB: W1 [128][128]
    {
        float4* d4 = reinterpret_cast<float4*>(sW1);
        const float4* s4 = reinterpret_cast<const float4*>(W1);
        for (int i = threadIdx.x; i < 4096; i += 256) d4[i] = s4[i];
    }
    __syncthreads();

    int e = blockIdx.x * 256 + threadIdx.x;
    if (e >= E) return;

    int row = edge_index[e];
    int col = edge_index[E + e];
    int gb  = batch[row];

    float h[128];
#pragma unroll
    for (int j = 0; j < 128; j++) h[j] = b1[j];

    accum_segment(h, node_attr   + (size_t)col * 32, sW1, 0);    // receiver
    accum_segment(h, node_attr   + (size_t)row * 32, sW1, 32);   // sender
    accum_segment(h, edge_attr   + (size_t)e   * 32, sW1, 64);   // edge
    accum_segment(h, global_attr + (size_t)gb  * 32, sW1, 96);   // global

#pragma unroll
    for (int j = 0; j < 128; j++) h[j] = fmaxf(h[j], 0.f);

    float o[32];
    layer2(h, W2, b2, o);

    float y[32];
    relu_ln_store(o, gamma, beta, edge_out + (size_t)e * 32, y);

    float* sa = send_agg + (size_t)row * 32;
    float* ra = recv_agg + (size_t)col * 32;
#pragma unroll
    for (int n = 0; n < 32; n++) {
        unsafeAtomicAdd(&sa[n], y[n]);
        unsafeAtomicAdd(&ra[n], y[n]);
    }
}

// ---------------------------------------------------------------------------
// Node model: n_in = [node_attr, global[batch], recv_agg, send_agg]
// node_new = LN(relu(relu(n_in@W1+b1)@W2+b2)); atomics into n2g;
// e2g += send_agg[n] (segment-sum of edge_new by edge_batch, re-derived).
// ---------------------------------------------------------------------------
__global__ __launch_bounds__(256, 2)
void node_kernel(const float* __restrict__ node_attr,
                 const float* __restrict__ global_attr,
                 const int* __restrict__ batch,
                 const float* __restrict__ send_agg,
                 const float* __restrict__ recv_agg,
                 const float* __restrict__ W1, const float* __restrict__ b1,
                 const float* __restrict__ W2, const float* __restrict__ b2,
                 const float* __restrict__ gamma, const float* __restrict__ beta,
                 float* __restrict__ node_out,
                 float* __restrict__ n2g, float* __restrict__ e2g,
                 int N)
{
    __shared__ float sW1[16384];
    {
        float4* d4 = reinterpret_cast<float4*>(sW1);
        const float4* s4 = reinterpret_cast<const float4*>(W1);
        for (int i = threadIdx.x; i < 4096; i += 256) d4[i] = s4[i];
    }
    __syncthreads();

    int n = blockIdx.x * 256 + threadIdx.x;
    if (n >= N) return;

    int gb = batch[n];

    float h[128];
#pragma unroll
    for (int j = 0; j < 128; j++) h[j] = b1[j];

    accum_segment(h, node_attr   + (size_t)n  * 32, sW1, 0);
    accum_segment(h, global_attr + (size_t)gb * 32, sW1, 32);
    accum_segment(h, recv_agg    + (size_t)n  * 32, sW1, 64);
    accum_segment(h, send_agg    + (size_t)n  * 32, sW1, 96);

#pragma unroll
    for (int j = 0; j < 128; j++) h[j] = fmaxf(h[j], 0.f);

    float o[32];
    layer2(h, W2, b2, o);

    float y[32];
    relu_ln_store(o, gamma, beta, node_out + (size_t)n * 32, y);

    // n2g += node_new ; e2g += send_agg[n]
    const float* sa = send_agg + (size_t)n * 32;
    float* ng_ = n2g + (size_t)gb * 32;
    float* eg_ = e2g + (size_t)gb * 32;
#pragma unroll
    for (int f = 0; f < 32; f++) {
        unsafeAtomicAdd(&ng_[f], y[f]);
        unsafeAtomicAdd(&eg_[f], sa[f]);
    }
}

// ---------------------------------------------------------------------------
// Global model: g_in = [n2g, e2g, global_attr] (96), out = relu(mlp(g_in))
// One block per graph, 128 threads (one per hidden unit).
// ---------------------------------------------------------------------------
__global__ void global_kernel(const float* __restrict__ n2g,
                              const float* __restrict__ e2g,
                              const float* __restrict__ global_attr,
                              const float* __restrict__ W1, const float* __restrict__ b1,
                              const float* __restrict__ W2, const float* __restrict__ b2,
                              float* __restrict__ out)
{
    __shared__ float gin[96];
    __shared__ float h[128];
    int g = blockIdx.x, t = threadIdx.x;
    if (t < 32) {
        gin[t]      = n2g[g * 32 + t];
        gin[32 + t] = e2g[g * 32 + t];
        gin[64 + t] = global_attr[g * 32 + t];
    }
    __syncthreads();
    float acc = b1[t];
#pragma unroll 1
    for (int k = 0; k < 96; k++) acc = fmaf(gin[k], W1[k * 128 + t], acc);
    h[t] = fmaxf(acc, 0.f);
    __syncthreads();
    if (t < 32) {
        float o = b2[t];
#pragma unroll 1
        for (int j = 0; j < 128; j++) o = fmaf(h[j], W2[j * 32 + t], o);
        out[g * 32 + t] = fmaxf(o, 0.f);
    }
}

// ---------------------------------------------------------------------------
// Launch
// ---------------------------------------------------------------------------
extern "C" void kernel_launch(void* const* d_in, const int* in_sizes, int n_in,
                              void* d_out, int out_size, void* d_ws, size_t ws_size,
                              hipStream_t stream)
{
    const float* edge_attr   = (const float*)d_in[0];
    const float* node_attr   = (const float*)d_in[1];
    const float* global_attr = (const float*)d_in[2];
    const int*   edge_index  = (const int*)d_in[3];
    const int*   batch       = (const int*)d_in[4];
    const float* eW1 = (const float*)d_in[5];
    const float* eb1 = (const float*)d_in[6];
    const float* eW2 = (const float*)d_in[7];
    const float* eb2 = (const float*)d_in[8];
    const float* eg  = (const float*)d_in[9];
    const float* eB  = (const float*)d_in[10];
    const float* nW1 = (const float*)d_in[11];
    const float* nb1 = (const float*)d_in[12];
    const float* nW2 = (const float*)d_in[13];
    const float* nb2 = (const float*)d_in[14];
    const float* ng  = (const float*)d_in[15];
    const float* nB  = (const float*)d_in[16];
    const float* gW1 = (const float*)d_in[17];
    const float* gb1 = (const float*)d_in[18];
    const float* gW2 = (const float*)d_in[19];
    const float* gb2 = (const float*)d_in[20];

    const int E = in_sizes[0] / 32;
    const int N = in_sizes[1] / 32;
    const int G = in_sizes[2] / 32;

    float* out      = (float*)d_out;
    float* edge_out = out;
    float* node_out = out + (size_t)E * 32;
    float* glob_out = out + (size_t)(E + N) * 32;

    // workspace: send_agg [N,32] | recv_agg [N,32] | n2g [G,32] | e2g [G,32]
    float* ws       = (float*)d_ws;
    float* send_agg = ws;
    float* recv_agg = ws + (size_t)N * 32;
    float* n2g      = ws + (size_t)2 * N * 32;
    float* e2g      = n2g + (size_t)G * 32;

    size_t zero_bytes = ((size_t)2 * N * 32 + (size_t)2 * G * 32) * sizeof(float);
    hipMemsetAsync(d_ws, 0, zero_bytes, stream);

    edge_kernel<<<(E + 255) / 256, 256, 0, stream>>>(
        edge_attr, node_attr, global_attr, edge_index, batch,
        eW1, eb1, eW2, eb2, eg, eB,
        edge_out, send_agg, recv_agg, E);

    node_kernel<<<(N + 255) / 256, 256, 0, stream>>>(
        node_attr, global_attr, batch, send_agg, recv_agg,
        nW1, nb1, nW2, nb2, ng, nB,
        node_out, n2g, e2g, N);

    global_kernel<<<G, 128, 0, stream>>>(
        n2g, e2g, global_attr, gW1, gb1, gW2, gb2, glob_out);
}

// Round 2
// 963.844 us; speedup vs baseline: 6.6468x; 6.6468x over previous
//
#include <hip/hip_runtime.h>
#include <cstdint>
#include <cstddef>

#define LN_EPS 1e-5f
#define STR 136   // padded LDS row stride in bf16 elems (136*2=272B, mult of 16)

typedef unsigned short u16;
typedef unsigned int   u32;
typedef __attribute__((ext_vector_type(8))) short bf16x8;
typedef __attribute__((ext_vector_type(4))) float f32x4;

__device__ __forceinline__ u16 f2bf(float f) {
    u32 x = __float_as_uint(f);
    return (u16)((x + 0x7fffu + ((x >> 16) & 1u)) >> 16);   // RNE, finite inputs
}

// load 32 fp32 from src, convert to bf16, store 64B to LDS (16B-aligned dst)
__device__ __forceinline__ void stage_row(const float* __restrict__ src, u16* dst) {
    const float4* s4 = reinterpret_cast<const float4*>(src);
    uint4* d4 = reinterpret_cast<uint4*>(dst);
#pragma unroll
    for (int q = 0; q < 4; q++) {
        float4 a = s4[2 * q], b = s4[2 * q + 1];
        uint4 o;
        o.x = f2bf(a.x) | ((u32)f2bf(a.y) << 16);
        o.y = f2bf(a.z) | ((u32)f2bf(a.w) << 16);
        o.z = f2bf(b.x) | ((u32)f2bf(b.y) << 16);
        o.w = f2bf(b.z) | ((u32)f2bf(b.w) << 16);
        d4[q] = o;
    }
}

// ---------------------------------------------------------------------------
// prep: convert W1 [128,128] -> W1T bf16 [n][k] stride 136; W2 [128,32] -> W2T
// ---------------------------------------------------------------------------
__global__ void prep_kernel(const float* __restrict__ eW1, const float* __restrict__ eW2,
                            const float* __restrict__ nW1, const float* __restrict__ nW2,
                            u16* eW1T, u16* eW2T, u16* nW1T, u16* nW2T)
{
    int idx = blockIdx.x * 256 + threadIdx.x;
    if (idx < 16384) {
        int k = idx >> 7, n = idx & 127;
        eW1T[n * STR + k] = f2bf(eW1[idx]);
        nW1T[n * STR + k] = f2bf(nW1[idx]);
    }
    if (idx < 4096) {
        int k = idx >> 5, n = idx & 31;
        eW2T[n * STR + k] = f2bf(eW2[idx]);
        nW2T[n * STR + k] = f2bf(nW2[idx]);
    }
}

// ---------------------------------------------------------------------------
// Edge model, MFMA. Each wave independently handles 32 edges.
// ---------------------------------------------------------------------------
__global__ __launch_bounds__(256, 2)
void edge_mfma(const float* __restrict__ edge_attr,
               const float* __restrict__ node_attr,
               const float* __restrict__ global_attr,
               const int* __restrict__ edge_index,
               const int* __restrict__ batch,
               const u16* __restrict__ W1T, const float* __restrict__ b1,
               const u16* __restrict__ W2T, const float* __restrict__ b2,
               const float* __restrict__ gamma, const float* __restrict__ beta,
               float* __restrict__ edge_out,
               float* __restrict__ send_agg, float* __restrict__ recv_agg,
               int E)
{
    __shared__ __align__(16) u16 sW1[128 * STR];
    __shared__ __align__(16) u16 sW2[32 * STR];
    __shared__ __align__(16) u16 sEin[4][32 * STR];
    __shared__ int2 sIdx[4][32];

    const int tid = threadIdx.x;
    {   // stage bf16 weights once per block
        const uint4* s1 = reinterpret_cast<const uint4*>(W1T);
        uint4* d1 = reinterpret_cast<uint4*>(sW1);
        for (int i = tid; i < 128 * STR / 8; i += 256) d1[i] = s1[i];
        const uint4* s2 = reinterpret_cast<const uint4*>(W2T);
        uint4* d2 = reinterpret_cast<uint4*>(sW2);
        for (int i = tid; i < 32 * STR / 8; i += 256) d2[i] = s2[i];
    }
    __syncthreads();

    const int wave = tid >> 6;
    const int lane = tid & 63;
    const int quad = lane >> 4;
    const int ln   = lane & 15;
    u16*  Ein  = sEin[wave];
    int2* idxb = sIdx[wave];

    const long e0 = ((long)blockIdx.x * 4 + wave) * 32;

    // ---- stage gathered e_in = [node[col] | node[row] | edge | global] ----
    {
        int eL  = lane >> 2;
        int seg = lane & 3;
#pragma unroll
        for (int t = 0; t < 2; t++, eL += 16) {
            long e = e0 + eL;
            long ec = e < E ? e : (long)E - 1;
            int row = edge_index[ec];
            int col = edge_index[(long)E + ec];
            const float* src;
            if (seg == 0)      { src = node_attr + (long)col * 32; idxb[eL].y = col; }
            else if (seg == 1) { src = node_attr + (long)row * 32; idxb[eL].x = row; }
            else if (seg == 2) { src = edge_attr + ec * 32; }
            else               { src = global_attr + (long)batch[row] * 32; }
            stage_row(src, Ein + eL * STR + seg * 32);
        }
    }

    // ---- GEMM1: H = relu(Ein @ W1 + b1), [32,128]x[128,128] ----
    f32x4 acc1[2][8];
#pragma unroll
    for (int mt = 0; mt < 2; mt++)
#pragma unroll
        for (int nt = 0; nt < 8; nt++) acc1[mt][nt] = (f32x4)0.f;

#pragma unroll
    for (int ks = 0; ks < 4; ks++) {
        const int ko = ks * 32 + quad * 8;
        bf16x8 a0 = *reinterpret_cast<const bf16x8*>(Ein + (ln) * STR + ko);
        bf16x8 a1 = *reinterpret_cast<const bf16x8*>(Ein + (16 + ln) * STR + ko);
#pragma unroll
        for (int nt = 0; nt < 8; nt++) {
            bf16x8 bf = *reinterpret_cast<const bf16x8*>(sW1 + (nt * 16 + ln) * STR + ko);
            acc1[0][nt] = __builtin_amdgcn_mfma_f32_16x16x32_bf16(a0, bf, acc1[0][nt], 0, 0, 0);
            acc1[1][nt] = __builtin_amdgcn_mfma_f32_16x16x32_bf16(a1, bf, acc1[1][nt], 0, 0, 0);
        }
    }

    // ---- bias+relu, H -> LDS (reuse Ein) in A-operand layout ----
#pragma unroll
    for (int nt = 0; nt < 8; nt++) {
        float bias = b1[nt * 16 + ln];
#pragma unroll
        for (int mt = 0; mt < 2; mt++)
#pragma unroll
            for (int r = 0; r < 4; r++) {
                float h = fmaxf(acc1[mt][nt][r] + bias, 0.f);
                int rowl = mt * 16 + quad * 4 + r;
                Ein[rowl * STR + nt * 16 + ln] = f2bf(h);
            }
    }

    // ---- GEMM2: O = H @ W2 + b2, [32,128]x[128,32] ----
    f32x4 acc2[2][2];
#pragma unroll
    for (int mt = 0; mt < 2; mt++)
#pragma unroll
        for (int nt = 0; nt < 2; nt++) acc2[mt][nt] = (f32x4)0.f;

#pragma unroll
    for (int ks = 0; ks < 4; ks++) {
        const int ko = ks * 32 + quad * 8;
        bf16x8 a0 = *reinterpret_cast<const bf16x8*>(Ein + (ln) * STR + ko);
        bf16x8 a1 = *reinterpret_cast<const bf16x8*>(Ein + (16 + ln) * STR + ko);
#pragma unroll
        for (int nt = 0; nt < 2; nt++) {
            bf16x8 bf = *reinterpret_cast<const bf16x8*>(sW2 + (nt * 16 + ln) * STR + ko);
            acc2[0][nt] = __builtin_amdgcn_mfma_f32_16x16x32_bf16(a0, bf, acc2[0][nt], 0, 0, 0);
            acc2[1][nt] = __builtin_amdgcn_mfma_f32_16x16x32_bf16(a1, bf, acc2[1][nt], 0, 0, 0);
        }
    }

    // ---- epilogue: relu, LN (shuffle over 16-lane group), store, atomics ----
    float g0 = gamma[ln],    g1 = gamma[16 + ln];
    float B0 = beta[ln],     B1 = beta[16 + ln];
    float bb0 = b2[ln],      bb1 = b2[16 + ln];

#pragma unroll
    for (int mt = 0; mt < 2; mt++) {
#pragma unroll
        for (int r = 0; r < 4; r++) {
            float v0 = fmaxf(acc2[mt][0][r] + bb0, 0.f);
            float v1 = fmaxf(acc2[mt][1][r] + bb1, 0.f);
            float s = v0 + v1, sq = v0 * v0 + v1 * v1;
#pragma unroll
            for (int m = 1; m < 16; m <<= 1) {
                s  += __shfl_xor(s,  m, 64);
                sq += __shfl_xor(sq, m, 64);
            }
            float mean = s * (1.f / 32.f);
            float var  = fmaxf(sq * (1.f / 32.f) - mean * mean, 0.f);
            float rs   = rsqrtf(var + LN_EPS);
            float y0 = (v0 - mean) * rs * g0 + B0;
            float y1 = (v1 - mean) * rs * g1 + B1;
            int rowl = mt * 16 + quad * 4 + r;
            long e = e0 + rowl;
            if (e < E) {
                edge_out[e * 32 + ln]      = y0;
                edge_out[e * 32 + 16 + ln] = y1;
                int2 rc = idxb[rowl];
                unsafeAtomicAdd(send_agg + (long)rc.x * 32 + ln,      y0);
                unsafeAtomicAdd(send_agg + (long)rc.x * 32 + 16 + ln, y1);
                unsafeAtomicAdd(recv_agg + (long)rc.y * 32 + ln,      y0);
                unsafeAtomicAdd(recv_agg + (long)rc.y * 32 + 16 + ln, y1);
            }
        }
    }
}

// ---------------------------------------------------------------------------
// Node model, MFMA. Same structure; segments [node | global | recv | send].
// ---------------------------------------------------------------------------
__global__ __launch_bounds__(256, 2)
void node_mfma(const float* __restrict__ node_attr,
               const float* __restrict__ global_attr,
               const int* __restrict__ batch,
               const float* __restrict__ send_agg,
               const float* __restrict__ recv_agg,
               const u16* __restrict__ W1T, const float* __restrict__ b1,
               const u16* __restrict__ W2T, const float* __restrict__ b2,
               const float* __restrict__ gamma, const float* __restrict__ beta,
               float* __restrict__ node_out,
               float* __restrict__ n2g, float* __restrict__ e2g,
               int N)
{
    __shared__ __align__(16) u16 sW1[128 * STR];
    __shared__ __align__(16) u16 sW2[32 * STR];
    __shared__ __align__(16) u16 sEin[4][32 * STR];
    __shared__ int sGb[4][32];

    const int tid = threadIdx.x;
    {
        const uint4* s1 = reinterpret_cast<const uint4*>(W1T);
        uint4* d1 = reinterpret_cast<uint4*>(sW1);
        for (int i = tid; i < 128 * STR / 8; i += 256) d1[i] = s1[i];
        const uint4* s2 = reinterpret_cast<const uint4*>(W2T);
        uint4* d2 = reinterpret_cast<uint4*>(sW2);
        for (int i = tid; i < 32 * STR / 8; i += 256) d2[i] = s2[i];
    }
    __syncthreads();

    const int wave = tid >> 6;
    const int lane = tid & 63;
    const int quad = lane >> 4;
    const int ln   = lane & 15;
    u16* Ein = sEin[wave];
    int* gbb = sGb[wave];

    const long n0 = ((long)blockIdx.x * 4 + wave) * 32;

    {
        int eL  = lane >> 2;
        int seg = lane & 3;
#pragma unroll
        for (int t = 0; t < 2; t++, eL += 16) {
            long n = n0 + eL;
            long nc = n < N ? n : (long)N - 1;
            const float* src;
            if (seg == 0)      { src = node_attr + nc * 32; }
            else if (seg == 1) { int gb = batch[nc]; src = global_attr + (long)gb * 32; gbb[eL] = gb; }
            else if (seg == 2) { src = recv_agg + nc * 32; }
            else               { src = send_agg + nc * 32; }
            stage_row(src, Ein + eL * STR + seg * 32);
        }
    }

    f32x4 acc1[2][8];
#pragma unroll
    for (int mt = 0; mt < 2; mt++)
#pragma unroll
        for (int nt = 0; nt < 8; nt++) acc1[mt][nt] = (f32x4)0.f;

#pragma unroll
    for (int ks = 0; ks < 4; ks++) {
        const int ko = ks * 32 + quad * 8;
        bf16x8 a0 = *reinterpret_cast<const bf16x8*>(Ein + (ln) * STR + ko);
        bf16x8 a1 = *reinterpret_cast<const bf16x8*>(Ein + (16 + ln) * STR + ko);
#pragma unroll
        for (int nt = 0; nt < 8; nt++) {
            bf16x8 bf = *reinterpret_cast<const bf16x8*>(sW1 + (nt * 16 + ln) * STR + ko);
            acc1[0][nt] = __builtin_amdgcn_mfma_f32_16x16x32_bf16(a0, bf, acc1[0][nt], 0, 0, 0);
            acc1[1][nt] = __builtin_amdgcn_mfma_f32_16x16x32_bf16(a1, bf, acc1[1][nt], 0, 0, 0);
        }
    }

#pragma unroll
    for (int nt = 0; nt < 8; nt++) {
        float bias = b1[nt * 16 + ln];
#pragma unroll
        for (int mt = 0; mt < 2; mt++)
#pragma unroll
            for (int r = 0; r < 4; r++) {
                float h = fmaxf(acc1[mt][nt][r] + bias, 0.f);
                int rowl = mt * 16 + quad * 4 + r;
                Ein[rowl * STR + nt * 16 + ln] = f2bf(h);
            }
    }

    f32x4 acc2[2][2];
#pragma unroll
    for (int mt = 0; mt < 2; mt++)
#pragma unroll
        for (int nt = 0; nt < 2; nt++) acc2[mt][nt] = (f32x4)0.f;

#pragma unroll
    for (int ks = 0; ks < 4; ks++) {
        const int ko = ks * 32 + quad * 8;
        bf16x8 a0 = *reinterpret_cast<const bf16x8*>(Ein + (ln) * STR + ko);
        bf16x8 a1 = *reinterpret_cast<const bf16x8*>(Ein + (16 + ln) * STR + ko);
#pragma unroll
        for (int nt = 0; nt < 2; nt++) {
            bf16x8 bf = *reinterpret_cast<const bf16x8*>(sW2 + (nt * 16 + ln) * STR + ko);
            acc2[0][nt] = __builtin_amdgcn_mfma_f32_16x16x32_bf16(a0, bf, acc2[0][nt], 0, 0, 0);
            acc2[1][nt] = __builtin_amdgcn_mfma_f32_16x16x32_bf16(a1, bf, acc2[1][nt], 0, 0, 0);
        }
    }

    float g0 = gamma[ln],    g1 = gamma[16 + ln];
    float B0 = beta[ln],     B1 = beta[16 + ln];
    float bb0 = b2[ln],      bb1 = b2[16 + ln];

#pragma unroll
    for (int mt = 0; mt < 2; mt++) {
#pragma unroll
        for (int r = 0; r < 4; r++) {
            float v0 = fmaxf(acc2[mt][0][r] + bb0, 0.f);
            float v1 = fmaxf(acc2[mt][1][r] + bb1, 0.f);
            float s = v0 + v1, sq = v0 * v0 + v1 * v1;
#pragma unroll
            for (int m = 1; m < 16; m <<= 1) {
                s  += __shfl_xor(s,  m, 64);
                sq += __shfl_xor(sq, m, 64);
            }
            float mean = s * (1.f / 32.f);
            float var  = fmaxf(sq * (1.f / 32.f) - mean * mean, 0.f);
            float rs   = rsqrtf(var + LN_EPS);
            float y0 = (v0 - mean) * rs * g0 + B0;
            float y1 = (v1 - mean) * rs * g1 + B1;
            int rowl = mt * 16 + quad * 4 + r;
            long n = n0 + rowl;
            if (n < N) {
                node_out[n * 32 + ln]      = y0;
                node_out[n * 32 + 16 + ln] = y1;
                int gb = gbb[rowl];
                unsafeAtomicAdd(n2g + (long)gb * 32 + ln,      y0);
                unsafeAtomicAdd(n2g + (long)gb * 32 + 16 + ln, y1);
                // e2g = segment_sum(edge_new by batch[row]) == sum of send_agg rows
                float sa0 = send_agg[n * 32 + ln];
                float sa1 = send_agg[n * 32 + 16 + ln];
                unsafeAtomicAdd(e2g + (long)gb * 32 + ln,      sa0);
                unsafeAtomicAdd(e2g + (long)gb * 32 + 16 + ln, sa1);
            }
        }
    }
}

// ---------------------------------------------------------------------------
// Global model (tiny, fp32 exact)
// ---------------------------------------------------------------------------
__global__ void global_kernel(const float* __restrict__ n2g,
                              const float* __restrict__ e2g,
                              const float* __restrict__ global_attr,
                              const float* __restrict__ W1, const float* __restrict__ b1,
                              const float* __restrict__ W2, const float* __restrict__ b2,
                              float* __restrict__ out)
{
    __shared__ float gin[96];
    __shared__ float h[128];
    int g = blockIdx.x, t = threadIdx.x;
    if (t < 32) {
        gin[t]      = n2g[g * 32 + t];
        gin[32 + t] = e2g[g * 32 + t];
        gin[64 + t] = global_attr[g * 32 + t];
    }
    __syncthreads();
    float acc = b1[t];
#pragma unroll 1
    for (int k = 0; k < 96; k++) acc = fmaf(gin[k], W1[k * 128 + t], acc);
    h[t] = fmaxf(acc, 0.f);
    __syncthreads();
    if (t < 32) {
        float o = b2[t];
#pragma unroll 1
        for (int j = 0; j < 128; j++) o = fmaf(h[j], W2[j * 32 + t], o);
        out[g * 32 + t] = fmaxf(o, 0.f);
    }
}

// ---------------------------------------------------------------------------
extern "C" void kernel_launch(void* const* d_in, const int* in_sizes, int n_in,
                              void* d_out, int out_size, void* d_ws, size_t ws_size,
                              hipStream_t stream)
{
    const float* edge_attr   = (const float*)d_in[0];
    const float* node_attr   = (const float*)d_in[1];
    const float* global_attr = (const float*)d_in[2];
    const int*   edge_index  = (const int*)d_in[3];
    const int*   batch       = (const int*)d_in[4];
    const float* eW1 = (const float*)d_in[5];
    const float* eb1 = (const float*)d_in[6];
    const float* eW2 = (const float*)d_in[7];
    const float* eb2 = (const float*)d_in[8];
    const float* eg  = (const float*)d_in[9];
    const float* eB  = (const float*)d_in[10];
    const float* nW1 = (const float*)d_in[11];
    const float* nb1 = (const float*)d_in[12];
    const float* nW2 = (const float*)d_in[13];
    const float* nb2 = (const float*)d_in[14];
    const float* ng  = (const float*)d_in[15];
    const float* nB  = (const float*)d_in[16];
    const float* gW1 = (const float*)d_in[17];
    const float* gb1 = (const float*)d_in[18];
    const float* gW2 = (const float*)d_in[19];
    const float* gb2 = (const float*)d_in[20];

    const int E = in_sizes[0] / 32;
    const int N = in_sizes[1] / 32;
    const int G = in_sizes[2] / 32;

    float* out      = (float*)d_out;
    float* edge_out = out;
    float* node_out = out + (size_t)E * 32;
    float* glob_out = out + (size_t)(E + N) * 32;

    // ws: send_agg[N,32] | recv_agg[N,32] | n2g[G,32] | e2g[G,32] | bf16 weights
    float* ws       = (float*)d_ws;
    float* send_agg = ws;
    float* recv_agg = ws + (size_t)N * 32;
    float* n2g      = ws + (size_t)2 * N * 32;
    float* e2g      = n2g + (size_t)G * 32;
    size_t fcount   = (size_t)2 * N * 32 + (size_t)2 * G * 32;
    u16* eW1T = (u16*)(ws + fcount);
    u16* eW2T = eW1T + 128 * STR;
    u16* nW1T = eW2T + 32 * STR;
    u16* nW2T = nW1T + 128 * STR;

    hipMemsetAsync(d_ws, 0, fcount * sizeof(float), stream);

    prep_kernel<<<64, 256, 0, stream>>>(eW1, eW2, nW1, nW2, eW1T, eW2T, nW1T, nW2T);

    edge_mfma<<<(E + 127) / 128, 256, 0, stream>>>(
        edge_attr, node_attr, global_attr, edge_index, batch,
        eW1T, eb1, eW2T, eb2, eg, eB,
        edge_out, send_agg, recv_agg, E);

    node_mfma<<<(N + 127) / 128, 256, 0, stream>>>(
        node_attr, global_attr, batch, send_agg, recv_agg,
        nW1T, nb1, nW2T, nb2, ng, nB,
        node_out, n2g, e2g, N);

    global_kernel<<<G, 128, 0, stream>>>(
        n2g, e2g, global_attr, gW1, gb1, gW2, gb2, glob_out);
}

// Round 3
// 799.528 us; speedup vs baseline: 8.0128x; 1.2055x over previous
//
#include <hip/hip_runtime.h>
#include <hip/hip_fp16.h>
#include <cstdint>
#include <cstddef>

#define LN_EPS 1e-5f
#define STR 136   // padded LDS row stride in bf16 elems (136*2=272B, 16B-mult)

typedef unsigned short u16;
typedef unsigned int   u32;
typedef __attribute__((ext_vector_type(8))) short bf16x8;
typedef __attribute__((ext_vector_type(4))) float f32x4;

__device__ __forceinline__ u16 f2bf(float f) {
    u32 x = __float_as_uint(f);
    return (u16)((x + 0x7fffu + ((x >> 16) & 1u)) >> 16);   // RNE, finite inputs
}

// 32 fp32 -> 32 bf16 into LDS (16B-aligned)
__device__ __forceinline__ void stage_row(const float* __restrict__ src, u16* dst) {
    const float4* s4 = reinterpret_cast<const float4*>(src);
    uint4* d4 = reinterpret_cast<uint4*>(dst);
#pragma unroll
    for (int q = 0; q < 4; q++) {
        float4 a = s4[2 * q], b = s4[2 * q + 1];
        uint4 o;
        o.x = f2bf(a.x) | ((u32)f2bf(a.y) << 16);
        o.y = f2bf(a.z) | ((u32)f2bf(a.w) << 16);
        o.z = f2bf(b.x) | ((u32)f2bf(b.y) << 16);
        o.w = f2bf(b.z) | ((u32)f2bf(b.w) << 16);
        d4[q] = o;
    }
}

__device__ __forceinline__ u32 h2_to_bf2(u32 h) {
    __half2 hv = *reinterpret_cast<__half2*>(&h);
    float lo = __half2float(__low2half(hv));
    float hi = __half2float(__high2half(hv));
    return (u32)f2bf(lo) | ((u32)f2bf(hi) << 16);
}

// 32 f16 -> 32 bf16 into LDS
__device__ __forceinline__ void stage_row_f16(const __half* __restrict__ src, u16* dst) {
    const uint4* s4 = reinterpret_cast<const uint4*>(src);  // 64 B = 4 x uint4
    uint4* d4 = reinterpret_cast<uint4*>(dst);
#pragma unroll
    for (int q = 0; q < 4; q++) {
        uint4 a = s4[q];
        uint4 o;
        o.x = h2_to_bf2(a.x); o.y = h2_to_bf2(a.y);
        o.z = h2_to_bf2(a.z); o.w = h2_to_bf2(a.w);
        d4[q] = o;
    }
}

// ---------------------------------------------------------------------------
// prep: W1 [128,128] -> W1T bf16 [n][k] stride STR; W2 [128,32] -> W2T
// ---------------------------------------------------------------------------
__global__ void prep_kernel(const float* __restrict__ eW1, const float* __restrict__ eW2,
                            const float* __restrict__ nW1, const float* __restrict__ nW2,
                            u16* eW1T, u16* eW2T, u16* nW1T, u16* nW2T)
{
    int idx = blockIdx.x * 256 + threadIdx.x;
    if (idx < 16384) {
        int k = idx >> 7, n = idx & 127;
        eW1T[n * STR + k] = f2bf(eW1[idx]);
        nW1T[n * STR + k] = f2bf(nW1[idx]);
    }
    if (idx < 4096) {
        int k = idx >> 5, n = idx & 31;
        eW2T[n * STR + k] = f2bf(eW2[idx]);
        nW2T[n * STR + k] = f2bf(nW2[idx]);
    }
}

// ---------------------------------------------------------------------------
// Edge model, MFMA. Each wave independently handles 32 edges.
// send/recv aggregation via packed-f16 atomics (half the op count/bytes).
// ---------------------------------------------------------------------------
__global__ __launch_bounds__(256, 2)
void edge_mfma(const float* __restrict__ edge_attr,
               const float* __restrict__ node_attr,
               const float* __restrict__ global_attr,
               const int* __restrict__ edge_index,
               const int* __restrict__ batch,
               const u16* __restrict__ W1T, const float* __restrict__ b1,
               const u16* __restrict__ W2T, const float* __restrict__ b2,
               const float* __restrict__ gamma, const float* __restrict__ beta,
               float* __restrict__ edge_out,
               __half* __restrict__ send_agg, __half* __restrict__ recv_agg,
               int E)
{
    __shared__ __align__(16) u16 sW1[128 * STR];
    __shared__ __align__(16) u16 sW2[32 * STR];
    __shared__ __align__(16) u16 sEin[4][32 * STR];
    __shared__ int2 sIdx[4][32];

    const int tid = threadIdx.x;
    {
        const uint4* s1 = reinterpret_cast<const uint4*>(W1T);
        uint4* d1 = reinterpret_cast<uint4*>(sW1);
        for (int i = tid; i < 128 * STR / 8; i += 256) d1[i] = s1[i];
        const uint4* s2 = reinterpret_cast<const uint4*>(W2T);
        uint4* d2 = reinterpret_cast<uint4*>(sW2);
        for (int i = tid; i < 32 * STR / 8; i += 256) d2[i] = s2[i];
    }
    __syncthreads();

    const int wave = tid >> 6;
    const int lane = tid & 63;
    const int quad = lane >> 4;
    const int ln   = lane & 15;
    u16*  Ein  = sEin[wave];
    int2* idxb = sIdx[wave];

    const long e0 = ((long)blockIdx.x * 4 + wave) * 32;

    // ---- stage gathered e_in = [node[col] | node[row] | edge | global] ----
    {
        int eL  = lane >> 2;
        int seg = lane & 3;
#pragma unroll
        for (int t = 0; t < 2; t++, eL += 16) {
            long e = e0 + eL;
            long ec = e < E ? e : (long)E - 1;
            int row = edge_index[ec];
            int col = edge_index[(long)E + ec];
            const float* src;
            if (seg == 0)      { src = node_attr + (long)col * 32; idxb[eL].y = col; }
            else if (seg == 1) { src = node_attr + (long)row * 32; idxb[eL].x = row; }
            else if (seg == 2) { src = edge_attr + ec * 32; }
            else               { src = global_attr + (long)batch[row] * 32; }
            stage_row(src, Ein + eL * STR + seg * 32);
        }
    }

    // ---- GEMM1: H = relu(Ein @ W1 + b1) ----
    f32x4 acc1[2][8];
#pragma unroll
    for (int mt = 0; mt < 2; mt++)
#pragma unroll
        for (int nt = 0; nt < 8; nt++) acc1[mt][nt] = (f32x4)0.f;

#pragma unroll
    for (int ks = 0; ks < 4; ks++) {
        const int ko = ks * 32 + quad * 8;
        bf16x8 a0 = *reinterpret_cast<const bf16x8*>(Ein + (ln) * STR + ko);
        bf16x8 a1 = *reinterpret_cast<const bf16x8*>(Ein + (16 + ln) * STR + ko);
#pragma unroll
        for (int nt = 0; nt < 8; nt++) {
            bf16x8 bf = *reinterpret_cast<const bf16x8*>(sW1 + (nt * 16 + ln) * STR + ko);
            acc1[0][nt] = __builtin_amdgcn_mfma_f32_16x16x32_bf16(a0, bf, acc1[0][nt], 0, 0, 0);
            acc1[1][nt] = __builtin_amdgcn_mfma_f32_16x16x32_bf16(a1, bf, acc1[1][nt], 0, 0, 0);
        }
    }

    // ---- bias+relu, H -> LDS (A-operand layout) ----
#pragma unroll
    for (int nt = 0; nt < 8; nt++) {
        float bias = b1[nt * 16 + ln];
#pragma unroll
        for (int mt = 0; mt < 2; mt++)
#pragma unroll
            for (int r = 0; r < 4; r++) {
                float h = fmaxf(acc1[mt][nt][r] + bias, 0.f);
                int rowl = mt * 16 + quad * 4 + r;
                Ein[rowl * STR + nt * 16 + ln] = f2bf(h);
            }
    }

    // ---- GEMM2 ----
    f32x4 acc2[2][2];
#pragma unroll
    for (int mt = 0; mt < 2; mt++)
#pragma unroll
        for (int nt = 0; nt < 2; nt++) acc2[mt][nt] = (f32x4)0.f;

#pragma unroll
    for (int ks = 0; ks < 4; ks++) {
        const int ko = ks * 32 + quad * 8;
        bf16x8 a0 = *reinterpret_cast<const bf16x8*>(Ein + (ln) * STR + ko);
        bf16x8 a1 = *reinterpret_cast<const bf16x8*>(Ein + (16 + ln) * STR + ko);
#pragma unroll
        for (int nt = 0; nt < 2; nt++) {
            bf16x8 bf = *reinterpret_cast<const bf16x8*>(sW2 + (nt * 16 + ln) * STR + ko);
            acc2[0][nt] = __builtin_amdgcn_mfma_f32_16x16x32_bf16(a0, bf, acc2[0][nt], 0, 0, 0);
            acc2[1][nt] = __builtin_amdgcn_mfma_f32_16x16x32_bf16(a1, bf, acc2[1][nt], 0, 0, 0);
        }
    }

    // ---- epilogue: relu, LN, nt-store, pk-f16 atomics ----
    float g0 = gamma[ln],    g1 = gamma[16 + ln];
    float B0 = beta[ln],     B1 = beta[16 + ln];
    float bb0 = b2[ln],      bb1 = b2[16 + ln];
    const bool evn = (ln & 1) == 0;
    const int fpair = evn ? ln : (15 + ln);   // even feature index of this lane's pair

#pragma unroll
    for (int mt = 0; mt < 2; mt++) {
#pragma unroll
        for (int r = 0; r < 4; r++) {
            float v0 = fmaxf(acc2[mt][0][r] + bb0, 0.f);
            float v1 = fmaxf(acc2[mt][1][r] + bb1, 0.f);
            float s = v0 + v1, sq = v0 * v0 + v1 * v1;
#pragma unroll
            for (int m = 1; m < 16; m <<= 1) {
                s  += __shfl_xor(s,  m, 64);
                sq += __shfl_xor(sq, m, 64);
            }
            float mean = s * (1.f / 32.f);
            float var  = fmaxf(sq * (1.f / 32.f) - mean * mean, 0.f);
            float rs   = rsqrtf(var + LN_EPS);
            float y0 = (v0 - mean) * rs * g0 + B0;
            float y1 = (v1 - mean) * rs * g1 + B1;
            // pair adjacent features across lane pairs (ln, ln^1)
            float p0 = __shfl_xor(y0, 1, 64);
            float p1 = __shfl_xor(y1, 1, 64);
            int rowl = mt * 16 + quad * 4 + r;
            long e = e0 + rowl;
            if (e < E) {
                __builtin_nontemporal_store(y0, &edge_out[e * 32 + ln]);
                __builtin_nontemporal_store(y1, &edge_out[e * 32 + 16 + ln]);
                __half2 val = evn
                    ? __halves2half2(__float2half_rn(y0), __float2half_rn(p0))
                    : __halves2half2(__float2half_rn(p1), __float2half_rn(y1));
                int2 rc = idxb[rowl];
                unsafeAtomicAdd(reinterpret_cast<__half2*>(send_agg + (long)rc.x * 32 + fpair), val);
                unsafeAtomicAdd(reinterpret_cast<__half2*>(recv_agg + (long)rc.y * 32 + fpair), val);
            }
        }
    }
}

// ---------------------------------------------------------------------------
// Node model, MFMA; n2g/e2g via block-level LDS reduction (batch is sorted ->
// a 128-node block spans ~1-2 graphs; 8 slots + global-atomic fallback).
// ---------------------------------------------------------------------------
__global__ __launch_bounds__(256, 2)
void node_mfma(const float* __restrict__ node_attr,
               const float* __restrict__ global_attr,
               const int* __restrict__ batch,
               const __half* __restrict__ send_agg,
               const __half* __restrict__ recv_agg,
               const u16* __restrict__ W1T, const float* __restrict__ b1,
               const u16* __restrict__ W2T, const float* __restrict__ b2,
               const float* __restrict__ gamma, const float* __restrict__ beta,
               float* __restrict__ node_out,
               float* __restrict__ n2g, float* __restrict__ e2g,
               int N)
{
    __shared__ __align__(16) u16 sW1[128 * STR];
    __shared__ __align__(16) u16 sEin[4][32 * STR];
    __shared__ int sGb[4][32];
    __shared__ float sRed[8][64];       // [slot][n2g 0..31 | e2g 32..63]
    __shared__ int sSlotGb[8];
    __shared__ int sGbFirst;

    const int tid = threadIdx.x;
    {
        const uint4* s1 = reinterpret_cast<const uint4*>(W1T);
        uint4* d1 = reinterpret_cast<uint4*>(sW1);
        for (int i = tid; i < 128 * STR / 8; i += 256) d1[i] = s1[i];
        for (int i = tid; i < 512; i += 256) ((float*)sRed)[i] = 0.f;
        if (tid < 8) sSlotGb[tid] = -1;
        if (tid == 0) {
            long nb = (long)blockIdx.x * 128;
            sGbFirst = batch[nb < N ? nb : N - 1];
        }
    }
    __syncthreads();

    const int wave = tid >> 6;
    const int lane = tid & 63;
    const int quad = lane >> 4;
    const int ln   = lane & 15;
    u16* Ein = sEin[wave];
    int* gbb = sGb[wave];
    const int gbF = sGbFirst;

    const long n0 = ((long)blockIdx.x * 4 + wave) * 32;

    {
        int eL  = lane >> 2;
        int seg = lane & 3;
#pragma unroll
        for (int t = 0; t < 2; t++, eL += 16) {
            long n = n0 + eL;
            long nc = n < N ? n : (long)N - 1;
            u16* dst = Ein + eL * STR + seg * 32;
            if (seg == 0)      { stage_row(node_attr + nc * 32, dst); }
            else if (seg == 1) { int gb = batch[nc]; gbb[eL] = gb;
                                 stage_row(global_attr + (long)gb * 32, dst); }
            else if (seg == 2) { stage_row_f16(recv_agg + nc * 32, dst); }
            else               { stage_row_f16(send_agg + nc * 32, dst); }
        }
    }

    f32x4 acc1[2][8];
#pragma unroll
    for (int mt = 0; mt < 2; mt++)
#pragma unroll
        for (int nt = 0; nt < 8; nt++) acc1[mt][nt] = (f32x4)0.f;

#pragma unroll
    for (int ks = 0; ks < 4; ks++) {
        const int ko = ks * 32 + quad * 8;
        bf16x8 a0 = *reinterpret_cast<const bf16x8*>(Ein + (ln) * STR + ko);
        bf16x8 a1 = *reinterpret_cast<const bf16x8*>(Ein + (16 + ln) * STR + ko);
#pragma unroll
        for (int nt = 0; nt < 8; nt++) {
            bf16x8 bf = *reinterpret_cast<const bf16x8*>(sW1 + (nt * 16 + ln) * STR + ko);
            acc1[0][nt] = __builtin_amdgcn_mfma_f32_16x16x32_bf16(a0, bf, acc1[0][nt], 0, 0, 0);
            acc1[1][nt] = __builtin_amdgcn_mfma_f32_16x16x32_bf16(a1, bf, acc1[1][nt], 0, 0, 0);
        }
    }

#pragma unroll
    for (int nt = 0; nt < 8; nt++) {
        float bias = b1[nt * 16 + ln];
#pragma unroll
        for (int mt = 0; mt < 2; mt++)
#pragma unroll
            for (int r = 0; r < 4; r++) {
                float h = fmaxf(acc1[mt][nt][r] + bias, 0.f);
                int rowl = mt * 16 + quad * 4 + r;
                Ein[rowl * STR + nt * 16 + ln] = f2bf(h);
            }
    }

    f32x4 acc2[2][2];
#pragma unroll
    for (int mt = 0; mt < 2; mt++)
#pragma unroll
        for (int nt = 0; nt < 2; nt++) acc2[mt][nt] = (f32x4)0.f;

#pragma unroll
    for (int ks = 0; ks < 4; ks++) {
        const int ko = ks * 32 + quad * 8;
        bf16x8 a0 = *reinterpret_cast<const bf16x8*>(Ein + (ln) * STR + ko);
        bf16x8 a1 = *reinterpret_cast<const bf16x8*>(Ein + (16 + ln) * STR + ko);
#pragma unroll
        for (int nt = 0; nt < 2; nt++) {
            // W2 B-fragments straight from global (8.7 KB, L1-hot)
            bf16x8 bf = *reinterpret_cast<const bf16x8*>(W2T + (nt * 16 + ln) * STR + ko);
            acc2[0][nt] = __builtin_amdgcn_mfma_f32_16x16x32_bf16(a0, bf, acc2[0][nt], 0, 0, 0);
            acc2[1][nt] = __builtin_amdgcn_mfma_f32_16x16x32_bf16(a1, bf, acc2[1][nt], 0, 0, 0);
        }
    }

    float g0 = gamma[ln],    g1 = gamma[16 + ln];
    float B0 = beta[ln],     B1 = beta[16 + ln];
    float bb0 = b2[ln],      bb1 = b2[16 + ln];

#pragma unroll
    for (int mt = 0; mt < 2; mt++) {
#pragma unroll
        for (int r = 0; r < 4; r++) {
            float v0 = fmaxf(acc2[mt][0][r] + bb0, 0.f);
            float v1 = fmaxf(acc2[mt][1][r] + bb1, 0.f);
            float s = v0 + v1, sq = v0 * v0 + v1 * v1;
#pragma unroll
            for (int m = 1; m < 16; m <<= 1) {
                s  += __shfl_xor(s,  m, 64);
                sq += __shfl_xor(sq, m, 64);
            }
            float mean = s * (1.f / 32.f);
            float var  = fmaxf(sq * (1.f / 32.f) - mean * mean, 0.f);
            float rs   = rsqrtf(var + LN_EPS);
            float y0 = (v0 - mean) * rs * g0 + B0;
            float y1 = (v1 - mean) * rs * g1 + B1;
            int rowl = mt * 16 + quad * 4 + r;
            long n = n0 + rowl;
            if (n < N) {
                node_out[n * 32 + ln]      = y0;
                node_out[n * 32 + 16 + ln] = y1;
                int gb = gbb[rowl];
                float sa0 = __half2float(send_agg[n * 32 + ln]);
                float sa1 = __half2float(send_agg[n * 32 + 16 + ln]);
                int slot = gb - gbF;
                if (slot >= 0 && slot < 8) {
                    if (ln == 0) sSlotGb[slot] = gb;
                    atomicAdd(&sRed[slot][ln],      y0);
                    atomicAdd(&sRed[slot][16 + ln], y1);
                    atomicAdd(&sRed[slot][32 + ln], sa0);
                    atomicAdd(&sRed[slot][48 + ln], sa1);
                } else {   // pathological fallback (shouldn't happen: sorted batch)
                    unsafeAtomicAdd(n2g + (long)gb * 32 + ln,      y0);
                    unsafeAtomicAdd(n2g + (long)gb * 32 + 16 + ln, y1);
                    unsafeAtomicAdd(e2g + (long)gb * 32 + ln,      sa0);
                    unsafeAtomicAdd(e2g + (long)gb * 32 + 16 + ln, sa1);
                }
            }
        }
    }

    __syncthreads();
    // flush block-level partials: 256 threads cover 8 slots x 64 feats in 2 steps
    for (int s = tid >> 6; s < 8; s += 4) {
        int f = tid & 63;
        int gb2 = sSlotGb[s];
        if (gb2 >= 0) {
            float v = sRed[s][f];
            float* dst = (f < 32) ? (n2g + (long)gb2 * 32 + f)
                                  : (e2g + (long)gb2 * 32 + (f - 32));
            unsafeAtomicAdd(dst, v);
        }
    }
}

// ---------------------------------------------------------------------------
// Global model (tiny, fp32 exact)
// ---------------------------------------------------------------------------
__global__ void global_kernel(const float* __restrict__ n2g,
                              const float* __restrict__ e2g,
                              const float* __restrict__ global_attr,
                              const float* __restrict__ W1, const float* __restrict__ b1,
                              const float* __restrict__ W2, const float* __restrict__ b2,
                              float* __restrict__ out)
{
    __shared__ float gin[96];
    __shared__ float h[128];
    int g = blockIdx.x, t = threadIdx.x;
    if (t < 32) {
        gin[t]      = n2g[g * 32 + t];
        gin[32 + t] = e2g[g * 32 + t];
        gin[64 + t] = global_attr[g * 32 + t];
    }
    __syncthreads();
    float acc = b1[t];
#pragma unroll 1
    for (int k = 0; k < 96; k++) acc = fmaf(gin[k], W1[k * 128 + t], acc);
    h[t] = fmaxf(acc, 0.f);
    __syncthreads();
    if (t < 32) {
        float o = b2[t];
#pragma unroll 1
        for (int j = 0; j < 128; j++) o = fmaf(h[j], W2[j * 32 + t], o);
        out[g * 32 + t] = fmaxf(o, 0.f);
    }
}

// ---------------------------------------------------------------------------
extern "C" void kernel_launch(void* const* d_in, const int* in_sizes, int n_in,
                              void* d_out, int out_size, void* d_ws, size_t ws_size,
                              hipStream_t stream)
{
    const float* edge_attr   = (const float*)d_in[0];
    const float* node_attr   = (const float*)d_in[1];
    const float* global_attr = (const float*)d_in[2];
    const int*   edge_index  = (const int*)d_in[3];
    const int*   batch       = (const int*)d_in[4];
    const float* eW1 = (const float*)d_in[5];
    const float* eb1 = (const float*)d_in[6];
    const float* eW2 = (const float*)d_in[7];
    const float* eb2 = (const float*)d_in[8];
    const float* eg  = (const float*)d_in[9];
    const float* eB  = (const float*)d_in[10];
    const float* nW1 = (const float*)d_in[11];
    const float* nb1 = (const float*)d_in[12];
    const float* nW2 = (const float*)d_in[13];
    const float* nb2 = (const float*)d_in[14];
    const float* ng  = (const float*)d_in[15];
    const float* nB  = (const float*)d_in[16];
    const float* gW1 = (const float*)d_in[17];
    const float* gb1 = (const float*)d_in[18];
    const float* gW2 = (const float*)d_in[19];
    const float* gb2 = (const float*)d_in[20];

    const int E = in_sizes[0] / 32;
    const int N = in_sizes[1] / 32;
    const int G = in_sizes[2] / 32;

    float* out      = (float*)d_out;
    float* edge_out = out;
    float* node_out = out + (size_t)E * 32;
    float* glob_out = out + (size_t)(E + N) * 32;

    // ws: send_agg f16[N*32] | recv_agg f16[N*32] | n2g f32[G*32] | e2g f32[G*32] | bf16 weights
    __half* send_agg = (__half*)d_ws;
    __half* recv_agg = send_agg + (size_t)N * 32;
    float*  n2g      = (float*)(recv_agg + (size_t)N * 32);
    float*  e2g      = n2g + (size_t)G * 32;
    u16* eW1T = (u16*)(e2g + (size_t)G * 32);
    u16* eW2T = eW1T + 128 * STR;
    u16* nW1T = eW2T + 32 * STR;
    u16* nW2T = nW1T + 128 * STR;

    size_t zero_bytes = (size_t)N * 32 * 2 * sizeof(__half)
                      + (size_t)G * 32 * 2 * sizeof(float);
    hipMemsetAsync(d_ws, 0, zero_bytes, stream);

    prep_kernel<<<64, 256, 0, stream>>>(eW1, eW2, nW1, nW2, eW1T, eW2T, nW1T, nW2T);

    edge_mfma<<<(E + 127) / 128, 256, 0, stream>>>(
        edge_attr, node_attr, global_attr, edge_index, batch,
        eW1T, eb1, eW2T, eb2, eg, eB,
        edge_out, send_agg, recv_agg, E);

    node_mfma<<<(N + 127) / 128, 256, 0, stream>>>(
        node_attr, global_attr, batch, send_agg, recv_agg,
        nW1T, nb1, nW2T, nb2, ng, nB,
        node_out, n2g, e2g, N);

    global_kernel<<<G, 128, 0, stream>>>(
        n2g, e2g, global_attr, gW1, gb1, gW2, gb2, glob_out);
}